// Round 1
// baseline (11973.069 us; speedup 1.0000x reference)
//
#include <hip/hip_runtime.h>

// Decoder_48378511622552 — fused GNN decoder for MI355X (gfx950)
// Scratch layout needs ~462 MB of d_ws.

#define HD   128
#define NC   50000
#define NF   150000
#define ECNT 400000
#define OUTD 3

typedef unsigned short ushort_t;
typedef unsigned int   uint_t;

__device__ __forceinline__ float blo(uint_t p){ return __uint_as_float(p << 16); }
__device__ __forceinline__ float bhi(uint_t p){ return __uint_as_float(p & 0xffff0000u); }
__device__ __forceinline__ float eluf(float x){ return x > 0.f ? x : expm1f(x); }

__device__ __forceinline__ ushort_t f2bf(float f){
  uint_t u = __float_as_uint(f);
  uint_t r = (u + 0x7fffu + ((u >> 16) & 1u)) >> 16;   // RNE
  return (ushort_t)r;
}

// chunked bf16 weight prep: out[(kc*128+j)*8 + t] = bf16(W[(kc*8+t)*128 + j])
// so the consumer reads one uint4 (8 bf16, K-contiguous for column j) per ds_read_b128.
__global__ void prep_w_kernel(const float* __restrict__ W, ushort_t* __restrict__ out, int K){
  int idx = blockIdx.x * blockDim.x + threadIdx.x;
  if (idx >= K * HD) return;
  int k = idx / HD, j = idx % HD;
  out[(((k >> 3) * HD + j) << 3) + (k & 7)] = f2bf(W[k * HD + j]);
}

__global__ void deg_kernel(const int* __restrict__ ei, int* __restrict__ deg){
  int e = blockIdx.x * blockDim.x + threadIdx.x;
  if (e < ECNT) atomicAdd(&deg[ei[ECNT + e]], 1);
}

enum { MODE_EDGE = 0, MODE_NODE = 1, MODE_DEC2 = 2, MODE_DEC1 = 3 };

// Fused 2-layer MLP (+elu, +residual, +LayerNorm, +segment-sum atomics).
// EDGE : in = [x[src] | x[dst] | ea[e]],  res = ea, out = ea (in-place), atomic agg[dst]
// NODE : in = [x[v]   | agg[v]/max(deg,1)], res = x,  out = x (in-place)
// DEC2 : in = [eac[r] | x[clusters[r]]],    res = eac, out = xb
// DEC1 : in = elu(delta @ dW0 + db0) computed inline; single GEMM + elu, no LN
template<int K1, int MODE>
__global__ __launch_bounds__(512, 2)
void mlp2_kernel(const ushort_t* __restrict__ W0c, const float* __restrict__ b0,
                 const ushort_t* __restrict__ W1c, const float* __restrict__ b1,
                 const float* __restrict__ gw,  const float* __restrict__ bw,
                 const float* __restrict__ in0, const float* __restrict__ in1,
                 const int* __restrict__ idx,  const int* __restrict__ deg,
                 float* __restrict__ outp, float* __restrict__ aggp,
                 int n_rows,
                 const float* __restrict__ dW0, const float* __restrict__ db0)
{
  constexpr int  TE    = 16;
  constexpr bool HAS2  = (MODE != MODE_DEC1);
  constexpr int  HOFF  = (MODE == MODE_EDGE) ? 0 : 128;   // where h / r overwrite sIn
  constexpr int  RESOFF= (MODE == MODE_EDGE) ? 256 : 0;   // residual columns (preserved)
  constexpr int  KQ    = K1 / 4;

  __shared__ __align__(16) ushort_t sW0[K1 * HD];
  __shared__ __align__(16) ushort_t sW1[HAS2 ? HD * HD : 8];
  __shared__ __align__(16) float    sIn[TE][K1];
  __shared__ float sB0[HD], sB1[HD], sG[HD], sBt[HD];

  const int tid = threadIdx.x;

  for (int ii = tid; ii < K1 * HD / 8; ii += 512)
    ((uint4*)sW0)[ii] = ((const uint4*)W0c)[ii];
  if constexpr (HAS2)
    for (int ii = tid; ii < HD * HD / 8; ii += 512)
      ((uint4*)sW1)[ii] = ((const uint4*)W1c)[ii];
  if (tid < HD){
    sB0[tid] = b0[tid];
    if constexpr (HAS2){ sB1[tid] = b1[tid]; sG[tid] = gw[tid]; sBt[tid] = bw[tid]; }
  }
  __syncthreads();

  const int j  = tid & 127;      // output column
  const int gg = tid >> 7;       // 0..3 -> rows gg*4 .. gg*4+3
  const int ntiles = (n_rows + TE - 1) / TE;

  for (int tile = blockIdx.x; tile < ntiles; tile += gridDim.x){
    const int row0 = tile * TE;

    // ---- stage inputs (gather + concat), f32, float4-vectorized ----
    for (int ii = tid; ii < TE * KQ; ii += 512){
      int e = ii / KQ, kq = ii % KQ, k = kq * 4;
      int rg = row0 + e;
      float4 v = make_float4(0.f, 0.f, 0.f, 0.f);
      if (rg < n_rows){
        if constexpr (MODE == MODE_EDGE){
          if (k < 128)      { int s = idx[rg];        v = *(const float4*)(in0 + (size_t)s * HD + k); }
          else if (k < 256) { int d = idx[ECNT + rg]; v = *(const float4*)(in0 + (size_t)d * HD + (k - 128)); }
          else              {                         v = *(const float4*)(in1 + (size_t)rg * HD + (k - 256)); }
        } else if constexpr (MODE == MODE_NODE){
          if (k < 128) v = *(const float4*)(in0 + (size_t)rg * HD + k);
          else {
            int dg = deg[rg]; float rd = 1.f / (float)(dg > 0 ? dg : 1);
            float4 t = *(const float4*)(in1 + (size_t)rg * HD + (k - 128));
            v.x = t.x * rd; v.y = t.y * rd; v.z = t.z * rd; v.w = t.w * rd;
          }
        } else if constexpr (MODE == MODE_DEC2){
          if (k < 128) v = *(const float4*)(in0 + (size_t)rg * HD + k);
          else { int c = idx[rg]; v = *(const float4*)(in1 + (size_t)c * HD + (k - 128)); }
        } else { // MODE_DEC1: h = elu(delta @ dW0 + db0) inline
          int c = idx[rg];
          float d0 = in0[c * 2]     - in1[rg * 2];
          float d1 = in0[c * 2 + 1] - in1[rg * 2 + 1];
          float4 wa = *(const float4*)(dW0 + k);
          float4 wb = *(const float4*)(dW0 + HD + k);
          float4 bb = *(const float4*)(db0 + k);
          v.x = eluf(fmaf(d0, wa.x, fmaf(d1, wb.x, bb.x)));
          v.y = eluf(fmaf(d0, wa.y, fmaf(d1, wb.y, bb.y)));
          v.z = eluf(fmaf(d0, wa.z, fmaf(d1, wb.z, bb.z)));
          v.w = eluf(fmaf(d0, wa.w, fmaf(d1, wb.w, bb.w)));
        }
      }
      *(float4*)(&sIn[e][k]) = v;
    }
    __syncthreads();

    // ---- layer 1: acc[e] = sIn[row] . W0[:,j] ----
    float acc[4] = {0.f, 0.f, 0.f, 0.f};
    for (int kc = 0; kc < K1 / 8; ++kc){
      uint4 wp = ((const uint4*)sW0)[kc * HD + j];
      float w0 = blo(wp.x), w1 = bhi(wp.x), w2 = blo(wp.y), w3 = bhi(wp.y);
      float w4 = blo(wp.z), w5 = bhi(wp.z), w6 = blo(wp.w), w7 = bhi(wp.w);
      #pragma unroll
      for (int e = 0; e < 4; ++e){
        const float4* ip = (const float4*)(&sIn[gg * 4 + e][kc * 8]);
        float4 a = ip[0], b = ip[1];
        float s = acc[e];
        s = fmaf(a.x, w0, s); s = fmaf(a.y, w1, s); s = fmaf(a.z, w2, s); s = fmaf(a.w, w3, s);
        s = fmaf(b.x, w4, s); s = fmaf(b.y, w5, s); s = fmaf(b.z, w6, s); s = fmaf(b.w, w7, s);
        acc[e] = s;
      }
    }
    __syncthreads();   // all sIn reads done before overwriting

    if constexpr (MODE == MODE_DEC1){
      #pragma unroll
      for (int e = 0; e < 4; ++e){
        int rg = row0 + gg * 4 + e;
        if (rg < n_rows) outp[(size_t)rg * HD + j] = eluf(acc[e] + sB0[j]);
      }
      continue;
    } else {
      // h = elu(acc + b0), stored over the consumed part of sIn
      #pragma unroll
      for (int e = 0; e < 4; ++e){
        float hv = acc[e] + sB0[j];
        sIn[gg * 4 + e][HOFF + j] = hv > 0.f ? hv : expm1f(hv);
      }
      __syncthreads();

      // ---- layer 2 ----
      float acc2[4] = {0.f, 0.f, 0.f, 0.f};
      for (int kc = 0; kc < HD / 8; ++kc){
        uint4 wp = ((const uint4*)sW1)[kc * HD + j];
        float w0 = blo(wp.x), w1 = bhi(wp.x), w2 = blo(wp.y), w3 = bhi(wp.y);
        float w4 = blo(wp.z), w5 = bhi(wp.z), w6 = blo(wp.w), w7 = bhi(wp.w);
        #pragma unroll
        for (int e = 0; e < 4; ++e){
          const float4* ip = (const float4*)(&sIn[gg * 4 + e][HOFF + kc * 8]);
          float4 a = ip[0], b = ip[1];
          float s = acc2[e];
          s = fmaf(a.x, w0, s); s = fmaf(a.y, w1, s); s = fmaf(a.z, w2, s); s = fmaf(a.w, w3, s);
          s = fmaf(b.x, w4, s); s = fmaf(b.y, w5, s); s = fmaf(b.z, w6, s); s = fmaf(b.w, w7, s);
          acc2[e] = s;
        }
      }
      __syncthreads();   // all h reads done

      // r = residual + o, staged for the LN row-reduction
      #pragma unroll
      for (int e = 0; e < 4; ++e){
        float r = acc2[e] + sB1[j] + sIn[gg * 4 + e][RESOFF + j];
        sIn[gg * 4 + e][HOFF + j] = r;
      }
      __syncthreads();

      // ---- LayerNorm: one wave per row (8 waves x 2 rows) ----
      const int wv = tid >> 6, lane = tid & 63;
      #pragma unroll
      for (int rr = 0; rr < 2; ++rr){
        int e  = wv * 2 + rr;
        int rg = row0 + e;
        float v0 = sIn[e][HOFF + lane], v1 = sIn[e][HOFF + 64 + lane];
        float s = v0 + v1, q = v0 * v0 + v1 * v1;
        #pragma unroll
        for (int o = 32; o; o >>= 1){ s += __shfl_xor(s, o); q += __shfl_xor(q, o); }
        float mu  = s * (1.f / 128.f);
        float var = q * (1.f / 128.f) - mu * mu;
        float rs  = rsqrtf(var + 1e-5f);
        float y0 = (v0 - mu) * rs * sG[lane]      + sBt[lane];
        float y1 = (v1 - mu) * rs * sG[64 + lane] + sBt[64 + lane];
        if (rg < n_rows){
          outp[(size_t)rg * HD + lane]      = y0;
          outp[(size_t)rg * HD + 64 + lane] = y1;
          if constexpr (MODE == MODE_EDGE){
            int d = idx[ECNT + rg];
            atomicAdd(aggp + (size_t)d * HD + lane,      y0);
            atomicAdd(aggp + (size_t)d * HD + 64 + lane, y1);
          }
        }
      }
      __syncthreads();
    }
  }
}

// out0 = elu(x @ oW + ob) : one wave per row
__global__ void outhead_kernel(const float* __restrict__ x, const float* __restrict__ oW,
                               const float* __restrict__ ob, float* __restrict__ out){
  int row  = (blockIdx.x * blockDim.x + threadIdx.x) >> 6;
  int lane = threadIdx.x & 63;
  if (row >= NF) return;
  const float* xr = x + (size_t)row * HD;
  float x0 = xr[lane], x1 = xr[64 + lane];
  float s0 = x0 * oW[lane * 3 + 0] + x1 * oW[(64 + lane) * 3 + 0];
  float s1 = x0 * oW[lane * 3 + 1] + x1 * oW[(64 + lane) * 3 + 1];
  float s2 = x0 * oW[lane * 3 + 2] + x1 * oW[(64 + lane) * 3 + 2];
  #pragma unroll
  for (int o = 32; o; o >>= 1){
    s0 += __shfl_xor(s0, o); s1 += __shfl_xor(s1, o); s2 += __shfl_xor(s2, o);
  }
  if (lane == 0){
    out[row * 3 + 0] = eluf(s0 + ob[0]);
    out[row * 3 + 1] = eluf(s1 + ob[1]);
    out[row * 3 + 2] = eluf(s2 + ob[2]);
  }
}

// out1 = edge_index_c as floats
__global__ void idxcopy_kernel(const int* __restrict__ ei, float* __restrict__ out){
  int i = blockIdx.x * blockDim.x + threadIdx.x;
  if (i < 2 * ECNT) out[i] = (float)ei[i];
}

extern "C" void kernel_launch(void* const* d_in, const int* in_sizes, int n_in,
                              void* d_out, int out_size, void* d_ws, size_t ws_size,
                              hipStream_t stream)
{
  const float* x_in  = (const float*)d_in[0];
  const float* ea_in = (const float*)d_in[1];
  const float* pos_c = (const float*)d_in[2];
  const float* pos_f = (const float*)d_in[3];
  const int*   ei    = (const int*)d_in[4];
  const int*   clus  = (const int*)d_in[5];
  // d_in[6] edge_index_f2c: structurally [arange(NF), clusters] -> unused
  const float* eW0 = (const float*)d_in[7];
  const float* eb0 = (const float*)d_in[8];
  const float* eW1 = (const float*)d_in[9];
  const float* eb1 = (const float*)d_in[10];
  const float* eg  = (const float*)d_in[11];
  const float* ebt = (const float*)d_in[12];
  const float* nW0 = (const float*)d_in[13];
  const float* nb0 = (const float*)d_in[14];
  const float* nW1 = (const float*)d_in[15];
  const float* nb1 = (const float*)d_in[16];
  const float* ng  = (const float*)d_in[17];
  const float* nbt = (const float*)d_in[18];
  const float* dW0 = (const float*)d_in[19];
  const float* db0 = (const float*)d_in[20];
  const float* dW1 = (const float*)d_in[21];
  const float* db1 = (const float*)d_in[22];
  const float* uW0 = (const float*)d_in[23];
  const float* ub0 = (const float*)d_in[24];
  const float* uW1 = (const float*)d_in[25];
  const float* ub1 = (const float*)d_in[26];
  const float* ug  = (const float*)d_in[27];
  const float* ubt = (const float*)d_in[28];
  const float* oW  = (const float*)d_in[29];
  const float* ob  = (const float*)d_in[30];

  char* w = (char*)d_ws;
  float* ea  = (float*)w;  w += (size_t)ECNT * HD * 4;   // 204.8 MB
  float* xa  = (float*)w;  w += (size_t)NC   * HD * 4;   //  25.6 MB
  float* xb  = (float*)w;  w += (size_t)NF   * HD * 4;   //  76.8 MB
  float* agg = (float*)w;  w += (size_t)NF   * HD * 4;   //  76.8 MB
  float* eac = (float*)w;  w += (size_t)NF   * HD * 4;   //  76.8 MB
  int*   deg = (int*)w;    w += (size_t)NF * 4;
  ushort_t* c_eW0 = (ushort_t*)w; w += 2 * 384 * HD * 2;
  ushort_t* c_eW1 = (ushort_t*)w; w += 2 * HD  * HD * 2;
  ushort_t* c_nW0 = (ushort_t*)w; w += 2 * 256 * HD * 2;
  ushort_t* c_nW1 = (ushort_t*)w; w += 2 * HD  * HD * 2;
  ushort_t* c_uW0 = (ushort_t*)w; w += 256 * HD * 2;
  ushort_t* c_uW1 = (ushort_t*)w; w += HD  * HD * 2;
  ushort_t* c_dW1 = (ushort_t*)w; w += HD  * HD * 2;

  hipMemcpyAsync(ea, ea_in, (size_t)ECNT * HD * 4, hipMemcpyDeviceToDevice, stream);
  hipMemcpyAsync(xa, x_in,  (size_t)NC   * HD * 4, hipMemcpyDeviceToDevice, stream);

  auto prep = [&](const float* W, ushort_t* o, int K){
    int n = K * HD;
    prep_w_kernel<<<(n + 255) / 256, 256, 0, stream>>>(W, o, K);
  };
  prep(eW0, c_eW0, 384); prep(eW0 + 384 * HD, c_eW0 + 384 * HD, 384);
  prep(eW1, c_eW1, 128); prep(eW1 + HD * HD,  c_eW1 + HD * HD,  128);
  prep(nW0, c_nW0, 256); prep(nW0 + 256 * HD, c_nW0 + 256 * HD, 256);
  prep(nW1, c_nW1, 128); prep(nW1 + HD * HD,  c_nW1 + HD * HD,  128);
  prep(uW0, c_uW0, 256); prep(uW1, c_uW1, 128); prep(dW1, c_dW1, 128);

  hipMemsetAsync(deg, 0, NF * 4, stream);
  deg_kernel<<<(ECNT + 255) / 256, 256, 0, stream>>>(ei, deg);

  auto gridFor = [](int rows){ int t = (rows + 15) / 16; return t < 2048 ? t : 2048; };

  // ---- pass 1 (n = NC, x = xa) ----
  for (int i = 0; i < 2; ++i){
    hipMemsetAsync(agg, 0, (size_t)NC * HD * 4, stream);
    mlp2_kernel<384, MODE_EDGE><<<gridFor(ECNT), 512, 0, stream>>>(
      c_eW0 + i * 384 * HD, eb0 + i * HD, c_eW1 + i * HD * HD, eb1 + i * HD,
      eg + i * HD, ebt + i * HD, xa, ea, ei, nullptr, ea, agg, ECNT, nullptr, nullptr);
    mlp2_kernel<256, MODE_NODE><<<gridFor(NC), 512, 0, stream>>>(
      c_nW0 + i * 256 * HD, nb0 + i * HD, c_nW1 + i * HD * HD, nb1 + i * HD,
      ng + i * HD, nbt + i * HD, xa, agg, nullptr, deg, xa, nullptr, NC, nullptr, nullptr);
  }

  // ---- decoder (seg_mean over arange is identity -> xb = t directly) ----
  mlp2_kernel<128, MODE_DEC1><<<gridFor(NF), 512, 0, stream>>>(
    c_dW1, db1, nullptr, nullptr, nullptr, nullptr,
    pos_c, pos_f, clus, nullptr, eac, nullptr, NF, dW0, db0);
  mlp2_kernel<256, MODE_DEC2><<<gridFor(NF), 512, 0, stream>>>(
    c_uW0, ub0, c_uW1, ub1, ug, ubt,
    eac, xa, clus, nullptr, xb, nullptr, NF, nullptr, nullptr);

  // ---- pass 2 (n = NF, x = xb) ----
  for (int i = 0; i < 2; ++i){
    hipMemsetAsync(agg, 0, (size_t)NF * HD * 4, stream);
    mlp2_kernel<384, MODE_EDGE><<<gridFor(ECNT), 512, 0, stream>>>(
      c_eW0 + i * 384 * HD, eb0 + i * HD, c_eW1 + i * HD * HD, eb1 + i * HD,
      eg + i * HD, ebt + i * HD, xb, ea, ei, nullptr, ea, agg, ECNT, nullptr, nullptr);
    mlp2_kernel<256, MODE_NODE><<<gridFor(NF), 512, 0, stream>>>(
      c_nW0 + i * 256 * HD, nb0 + i * HD, c_nW1 + i * HD * HD, nb1 + i * HD,
      ng + i * HD, nbt + i * HD, xb, agg, nullptr, deg, xb, nullptr, NF, nullptr, nullptr);
  }

  float* out = (float*)d_out;
  outhead_kernel<<<(NF + 3) / 4, 256, 0, stream>>>(xb, oW, ob, out);
  idxcopy_kernel<<<(2 * ECNT + 255) / 256, 256, 0, stream>>>(ei, out + (size_t)NF * OUTD);
}

// Round 2
// 2961.410 us; speedup vs baseline: 4.0430x; 4.0430x over previous
//
#include <hip/hip_runtime.h>

// Decoder_48378511622552 — CSR-sorted, bf16, MFMA fused GNN decoder (gfx950)

#define HD   128
#define NC   50000
#define NF   150000
#define ECNT 400000
#define OUTD 3
#define SCB  512
#define NB_SCAN ((NF + SCB - 1) / SCB)   // 293

typedef unsigned short u16;
typedef unsigned int   u32;
typedef short bf16x8 __attribute__((ext_vector_type(8)));
typedef float f32x4  __attribute__((ext_vector_type(4)));

__device__ __forceinline__ float bf2f(u32 u){ return __uint_as_float(u << 16); }
__device__ __forceinline__ u16 f2bf(float f){
  u32 u = __float_as_uint(f);
  return (u16)((u + 0x7fffu + ((u >> 16) & 1u)) >> 16);   // RNE
}
__device__ __forceinline__ u32 pk2(float a, float b){ return (u32)f2bf(a) | ((u32)f2bf(b) << 16); }
__device__ __forceinline__ float eluf(float x){ return x > 0.f ? x : expm1f(x); }

// ---------------- prep kernels ----------------

// chunked bf16 weights: out[((k>>3)*128 + j)*8 + (k&7)] = bf16(W[k*128 + j])
// -> uint4 at (kc*128+j) = 8 K-contiguous bf16 of column j  (B^T fragment layout)
__global__ void prep_w_kernel(const float* __restrict__ W, u16* __restrict__ out, int K){
  int idx = blockIdx.x * blockDim.x + threadIdx.x;
  if (idx >= K * HD) return;
  int k = idx / HD, j = idx % HD;
  out[(((k >> 3) * HD + j) << 3) + (k & 7)] = f2bf(W[k * HD + j]);
}

__global__ void f32_to_bf16_vec(const float* __restrict__ in, u16* __restrict__ out, int n8){
  int i = blockIdx.x * blockDim.x + threadIdx.x;
  if (i >= n8) return;
  float4 f0 = ((const float4*)in)[i * 2];
  float4 f1 = ((const float4*)in)[i * 2 + 1];
  ((uint4*)out)[i] = make_uint4(pk2(f0.x,f0.y), pk2(f0.z,f0.w), pk2(f1.x,f1.y), pk2(f1.z,f1.w));
}

__global__ void deg_kernel(const int* __restrict__ ei, int* __restrict__ deg){
  int e = blockIdx.x * blockDim.x + threadIdx.x;
  if (e < ECNT) atomicAdd(&deg[ei[ECNT + e]], 1);
}

__global__ void scanA_kernel(const int* __restrict__ deg, int* __restrict__ part){
  __shared__ int s[SCB];
  int t = threadIdx.x, i = blockIdx.x * SCB + t;
  s[t] = (i < NF) ? deg[i] : 0;
  __syncthreads();
  for (int off = SCB/2; off; off >>= 1){ if (t < off) s[t] += s[t + off]; __syncthreads(); }
  if (t == 0) part[blockIdx.x] = s[0];
}

__global__ void scanB_kernel(int* __restrict__ part){
  __shared__ int s[SCB];
  int t = threadIdx.x;
  int v = (t < NB_SCAN) ? part[t] : 0;
  s[t] = v; __syncthreads();
  for (int off = 1; off < SCB; off <<= 1){
    int x = (t >= off) ? s[t - off] : 0;
    __syncthreads(); s[t] += x; __syncthreads();
  }
  if (t < NB_SCAN) part[t] = s[t] - v;   // exclusive
}

__global__ void scanC_kernel(const int* __restrict__ deg, const int* __restrict__ part,
                             int* __restrict__ rowptr){
  __shared__ int s[SCB];
  int t = threadIdx.x, i = blockIdx.x * SCB + t;
  int v = (i < NF) ? deg[i] : 0;
  s[t] = v; __syncthreads();
  for (int off = 1; off < SCB; off <<= 1){
    int x = (t >= off) ? s[t - off] : 0;
    __syncthreads(); s[t] += x; __syncthreads();
  }
  int excl = part[blockIdx.x] + s[t] - v;
  if (i < NF) rowptr[i] = excl;
  if (i == NF - 1) rowptr[NF] = excl + v;
}

__global__ void build_perm_kernel(const int* __restrict__ ei, int* __restrict__ cursor,
                                  int* __restrict__ perm, int* __restrict__ esrc,
                                  int* __restrict__ edst){
  int e = blockIdx.x * blockDim.x + threadIdx.x;
  if (e >= ECNT) return;
  int sI = ei[e], d = ei[ECNT + e];
  int p = atomicAdd(&cursor[d], 1);
  perm[p] = e; esrc[p] = sI; edst[p] = d;
}

__global__ void permute_ea_kernel(const float* __restrict__ ea_in, const int* __restrict__ perm,
                                  u16* __restrict__ ea_s){
  int i = blockIdx.x * blockDim.x + threadIdx.x;
  if (i >= ECNT * 16) return;
  int p = i >> 4, c = i & 15;
  int e = perm[p];
  const float4* src = (const float4*)(ea_in + (size_t)e * HD + c * 8);
  float4 f0 = src[0], f1 = src[1];
  ((uint4*)ea_s)[(size_t)p * 16 + c] =
      make_uint4(pk2(f0.x,f0.y), pk2(f0.z,f0.w), pk2(f1.x,f1.y), pk2(f1.z,f1.w));
}

// ---------------- fused MFMA MLP ----------------
enum { M_EDGE = 0, M_NODE = 1, M_DEC2 = 2, M_DEC1 = 3 };

// Block: 512 thr = 8 waves, wave grid 2(M)x4(N), wave tile 32x32 (16x16x32 MFMA).
// Tile: 64 rows x 128 cols out. LDS: sIn [64][K1] bf16 swizzled + h [64][128] bf16.
template<int MODE>
__global__ __launch_bounds__(512, 2)
void mfma_mlp(const u16* __restrict__ W0c, const float* __restrict__ b0,
              const u16* __restrict__ W1c, const float* __restrict__ b1,
              const float* __restrict__ gw, const float* __restrict__ bw,
              const u16* __restrict__ xtab, const u16* __restrict__ ea,
              const int* __restrict__ esrc, const int* __restrict__ edst,
              const int* __restrict__ rowptr, const int* __restrict__ clus,
              u16* __restrict__ outp, int n_rows,
              const float* __restrict__ dW0, const float* __restrict__ db0,
              const float* __restrict__ pos_c, const float* __restrict__ pos_f)
{
  constexpr int  K1   = (MODE == M_EDGE) ? 384 : (MODE == M_DEC1) ? 128 : 256;
  constexpr int  NK1  = K1 / 32;
  constexpr bool HAS2 = (MODE != M_DEC1);
  constexpr int  ROWB = K1 * 2;
  constexpr int  RESB = (MODE == M_EDGE) ? 512 : 0;   // residual byte offset in sIn row

  __shared__ __align__(16) char ldsA[64 * ROWB];
  __shared__ __align__(16) char ldsH[HAS2 ? 64 * 256 : 16];

  const int tid  = threadIdx.x;
  const int lane = tid & 63;
  const int wid  = tid >> 6;
  const int ln   = lane & 15, kq = lane >> 4;
  const int m0   = (wid & 1) * 32;
  const int ncol = (wid >> 1) * 32;

  // weight fragments in registers (per-wave N-slice)
  bf16x8 b1f[NK1][2];
  #pragma unroll
  for (int k0 = 0; k0 < NK1; ++k0)
    #pragma unroll
    for (int nt = 0; nt < 2; ++nt)
      b1f[k0][nt] = *(const bf16x8*)(W0c + (((size_t)((k0*4 + kq)*HD + ncol + nt*16 + ln)) << 3));
  bf16x8 b2f[HAS2 ? 4 : 1][2];
  if constexpr (HAS2){
    #pragma unroll
    for (int k0 = 0; k0 < 4; ++k0)
      #pragma unroll
      for (int nt = 0; nt < 2; ++nt)
        b2f[k0][nt] = *(const bf16x8*)(W1c + (((size_t)((k0*4 + kq)*HD + ncol + nt*16 + ln)) << 3));
  }
  float b0v[2], b1v[2] = {0.f, 0.f};
  #pragma unroll
  for (int nt = 0; nt < 2; ++nt) b0v[nt] = b0[ncol + nt*16 + ln];
  float gl0 = 0.f, gl1 = 0.f, bt0 = 0.f, bt1 = 0.f;
  if constexpr (HAS2){
    #pragma unroll
    for (int nt = 0; nt < 2; ++nt) b1v[nt] = b1[ncol + nt*16 + ln];
    gl0 = gw[lane]; gl1 = gw[64 + lane]; bt0 = bw[lane]; bt1 = bw[64 + lane];
  }

  const int tiles = (n_rows + 63) >> 6;

  auto eload = [&](int tile, uint4* pre){
    int row0 = tile << 6;
    #pragma unroll
    for (int ch = 0; ch < 6; ++ch){
      int i = tid + ch * 512;
      int row = i / 48, kk = i % 48;
      int rg = row0 + row;                      // ECNT % 64 == 0: no guard needed
      const u16* p;
      if (kk < 16)      p = xtab + (((size_t)esrc[rg]) << 7) + (kk << 3);
      else if (kk < 32) p = xtab + (((size_t)edst[rg]) << 7) + ((kk - 16) << 3);
      else              p = ea   + (((size_t)rg) << 7) + ((kk - 32) << 3);
      pre[ch] = *(const uint4*)p;
    }
  };

  uint4 pre[(MODE == M_EDGE) ? 6 : 1];
  if constexpr (MODE == M_EDGE) eload(blockIdx.x, pre);

  for (int tile = blockIdx.x; tile < tiles; tile += gridDim.x){
    const int row0 = tile << 6;

    // ---------- stage ----------
    if constexpr (MODE == M_EDGE){
      #pragma unroll
      for (int ch = 0; ch < 6; ++ch){
        int i = tid + ch * 512;
        int row = i / 48, kk = i % 48;
        *(uint4*)(ldsA + row * ROWB + ((kk * 16) ^ ((row & 7) << 4))) = pre[ch];
      }
    } else if constexpr (MODE == M_NODE){
      #pragma unroll
      for (int ch = 0; ch < 2; ++ch){
        int i = tid + ch * 512;
        int row = i >> 4, kk = i & 15;
        int rg = row0 + row;
        if (rg < n_rows){
          uint4 v = *(const uint4*)(xtab + (((size_t)rg) << 7) + (kk << 3));
          *(uint4*)(ldsA + row * ROWB + ((kk * 16) ^ ((row & 7) << 4))) = v;
        }
      }
      // CSR mean: wave wid handles 8 nodes, lane covers col pair (2*lane, 2*lane+1)
      for (int s = 0; s < 8; ++s){
        int nd = wid * 8 + s, rg = row0 + nd;
        if (rg < n_rows){
          int rp0 = rowptr[rg], rp1 = rowptr[rg + 1];
          float s0 = 0.f, s1 = 0.f;
          for (int i2 = rp0; i2 < rp1; ++i2){
            u32 u = *(const u32*)(ea + (((size_t)i2) << 7) + (lane << 1));
            s0 += bf2f(u & 0xffffu); s1 += bf2f(u >> 16);
          }
          int dg = rp1 - rp0;
          float rd = 1.f / (float)(dg > 0 ? dg : 1);
          *(u32*)(ldsA + nd * ROWB + ((256 + (lane << 2)) ^ ((nd & 7) << 4))) = pk2(s0 * rd, s1 * rd);
        }
      }
    } else if constexpr (MODE == M_DEC2){
      #pragma unroll
      for (int ch = 0; ch < 4; ++ch){
        int i = tid + ch * 512;
        int row = i >> 5, kk = i & 31;
        int rg = row0 + row;
        if (rg < n_rows){
          const u16* p = (kk < 16) ? (ea   + (((size_t)rg) << 7) + (kk << 3))
                                   : (xtab + (((size_t)clus[rg]) << 7) + ((kk - 16) << 3));
          uint4 v = *(const uint4*)p;
          *(uint4*)(ldsA + row * ROWB + ((kk * 16) ^ ((row & 7) << 4))) = v;
        }
      }
    } else { // M_DEC1: h = elu(delta @ dW0 + db0) inline
      #pragma unroll
      for (int ch = 0; ch < 2; ++ch){
        int i = tid + ch * 512;
        int row = i >> 4, c8 = i & 15;
        int rg = row0 + row;
        if (rg < n_rows){
          int cl = clus[rg];
          float d0 = pos_c[cl * 2]     - pos_f[rg * 2];
          float d1 = pos_c[cl * 2 + 1] - pos_f[rg * 2 + 1];
          u32 wq[4];
          #pragma unroll
          for (int q = 0; q < 4; ++q){
            int c = c8 * 8 + q * 2;
            float va = eluf(fmaf(d0, dW0[c],     fmaf(d1, dW0[HD + c],     db0[c])));
            float vb = eluf(fmaf(d0, dW0[c + 1], fmaf(d1, dW0[HD + c + 1], db0[c + 1])));
            wq[q] = pk2(va, vb);
          }
          *(uint4*)(ldsA + row * ROWB + ((c8 * 16) ^ ((row & 7) << 4))) =
              make_uint4(wq[0], wq[1], wq[2], wq[3]);
        }
      }
    }
    __syncthreads();   // A: stage visible

    if constexpr (MODE == M_EDGE){
      if (tile + (int)gridDim.x < tiles) eload(tile + gridDim.x, pre);   // T14 prefetch
    }

    // ---------- layer 1 ----------
    const f32x4 zz = {0.f, 0.f, 0.f, 0.f};
    f32x4 c1[2][2] = {{zz, zz}, {zz, zz}};
    #pragma unroll
    for (int k0 = 0; k0 < NK1; ++k0){
      int r0 = m0 + ln, r1 = m0 + 16 + ln;
      bf16x8 a0 = *(const bf16x8*)(ldsA + r0 * ROWB + (((k0 * 64) + (kq << 4)) ^ ((r0 & 7) << 4)));
      bf16x8 a1 = *(const bf16x8*)(ldsA + r1 * ROWB + (((k0 * 64) + (kq << 4)) ^ ((r1 & 7) << 4)));
      c1[0][0] = __builtin_amdgcn_mfma_f32_16x16x32_bf16(a0, b1f[k0][0], c1[0][0], 0, 0, 0);
      c1[0][1] = __builtin_amdgcn_mfma_f32_16x16x32_bf16(a0, b1f[k0][1], c1[0][1], 0, 0, 0);
      c1[1][0] = __builtin_amdgcn_mfma_f32_16x16x32_bf16(a1, b1f[k0][0], c1[1][0], 0, 0, 0);
      c1[1][1] = __builtin_amdgcn_mfma_f32_16x16x32_bf16(a1, b1f[k0][1], c1[1][1], 0, 0, 0);
    }

    if constexpr (MODE == M_DEC1){
      __syncthreads();  // B: all layer-1 LDS reads done before overwrite
      #pragma unroll
      for (int mi = 0; mi < 2; ++mi)
        #pragma unroll
        for (int nt = 0; nt < 2; ++nt)
          #pragma unroll
          for (int r = 0; r < 4; ++r){
            float v = eluf(c1[mi][nt][r] + b0v[nt]);
            int row = m0 + mi * 16 + kq * 4 + r;
            int col = ncol + nt * 16 + ln;
            *(u16*)(ldsA + row * ROWB + ((col * 2) ^ ((row & 7) << 4))) = f2bf(v);
          }
      __syncthreads();  // C
    } else {
      // h = elu(.) -> ldsH (bf16, swizzled)
      #pragma unroll
      for (int mi = 0; mi < 2; ++mi)
        #pragma unroll
        for (int nt = 0; nt < 2; ++nt)
          #pragma unroll
          for (int r = 0; r < 4; ++r){
            float v = eluf(c1[mi][nt][r] + b0v[nt]);
            int row = m0 + mi * 16 + kq * 4 + r;
            int col = ncol + nt * 16 + ln;
            *(u16*)(ldsH + row * 256 + ((col * 2) ^ ((row & 7) << 4))) = f2bf(v);
          }
      __syncthreads();  // B: h complete + layer-1 sIn reads done

      // ---------- layer 2 ----------
      f32x4 c2[2][2] = {{zz, zz}, {zz, zz}};
      #pragma unroll
      for (int k0 = 0; k0 < 4; ++k0){
        int r0 = m0 + ln, r1 = m0 + 16 + ln;
        bf16x8 a0 = *(const bf16x8*)(ldsH + r0 * 256 + (((k0 * 64) + (kq << 4)) ^ ((r0 & 7) << 4)));
        bf16x8 a1 = *(const bf16x8*)(ldsH + r1 * 256 + (((k0 * 64) + (kq << 4)) ^ ((r1 & 7) << 4)));
        c2[0][0] = __builtin_amdgcn_mfma_f32_16x16x32_bf16(a0, b2f[k0][0], c2[0][0], 0, 0, 0);
        c2[0][1] = __builtin_amdgcn_mfma_f32_16x16x32_bf16(a0, b2f[k0][1], c2[0][1], 0, 0, 0);
        c2[1][0] = __builtin_amdgcn_mfma_f32_16x16x32_bf16(a1, b2f[k0][0], c2[1][0], 0, 0, 0);
        c2[1][1] = __builtin_amdgcn_mfma_f32_16x16x32_bf16(a1, b2f[k0][1], c2[1][1], 0, 0, 0);
      }
      // r = acc2 + b1 + residual, written in place over the residual bf16 (per-col ownership)
      #pragma unroll
      for (int mi = 0; mi < 2; ++mi)
        #pragma unroll
        for (int nt = 0; nt < 2; ++nt)
          #pragma unroll
          for (int r = 0; r < 4; ++r){
            int row = m0 + mi * 16 + kq * 4 + r;
            int col = ncol + nt * 16 + ln;
            u16* rp = (u16*)(ldsA + row * ROWB + ((RESB + col * 2) ^ ((row & 7) << 4)));
            float res = bf2f(*rp);
            *rp = f2bf(c2[mi][nt][r] + b1v[nt] + res);
          }
      __syncthreads();  // C
    }

    // ---------- LayerNorm + packed coalesced store ----------
    #pragma unroll
    for (int rr = 0; rr < 8; ++rr){
      int e = wid * 8 + rr, rg = row0 + e;
      float v0 = bf2f(*(u16*)(ldsA + e * ROWB + ((RESB + lane * 2) ^ ((e & 7) << 4))));
      float v1 = bf2f(*(u16*)(ldsA + e * ROWB + ((RESB + (64 + lane) * 2) ^ ((e & 7) << 4))));
      float y0, y1;
      if constexpr (MODE == M_DEC1){ y0 = v0; y1 = v1; }
      else {
        float s = v0 + v1, q = v0 * v0 + v1 * v1;
        #pragma unroll
        for (int o = 32; o; o >>= 1){ s += __shfl_xor(s, o); q += __shfl_xor(q, o); }
        float mu  = s * (1.f / 128.f);
        float var = q * (1.f / 128.f) - mu * mu;
        float rs  = rsqrtf(var + 1e-5f);
        y0 = (v0 - mu) * rs * gl0 + bt0;
        y1 = (v1 - mu) * rs * gl1 + bt1;
      }
      int sl = (lane << 1) & 63;
      float a0s = __shfl(y0, sl), a1s = __shfl(y0, sl + 1);
      float b0s = __shfl(y1, sl), b1s = __shfl(y1, sl + 1);
      float pa = lane < 32 ? a0s : b0s;
      float pb = lane < 32 ? a1s : b1s;
      if (rg < n_rows)
        ((u32*)(outp + (((size_t)rg) << 7)))[lane] = pk2(pa, pb);
    }
    __syncthreads();  // D: LN reads done before next stage overwrites
  }
}

// out0 = elu(x @ oW + ob)
__global__ void outhead_kernel(const u16* __restrict__ x, const float* __restrict__ oW,
                               const float* __restrict__ ob, float* __restrict__ out){
  int row  = (blockIdx.x * blockDim.x + threadIdx.x) >> 6;
  int lane = threadIdx.x & 63;
  if (row >= NF) return;
  float x0 = bf2f(x[((size_t)row << 7) + lane]);
  float x1 = bf2f(x[((size_t)row << 7) + 64 + lane]);
  float s0 = x0 * oW[lane * 3 + 0] + x1 * oW[(64 + lane) * 3 + 0];
  float s1 = x0 * oW[lane * 3 + 1] + x1 * oW[(64 + lane) * 3 + 1];
  float s2 = x0 * oW[lane * 3 + 2] + x1 * oW[(64 + lane) * 3 + 2];
  #pragma unroll
  for (int o = 32; o; o >>= 1){
    s0 += __shfl_xor(s0, o); s1 += __shfl_xor(s1, o); s2 += __shfl_xor(s2, o);
  }
  if (lane == 0){
    out[row * 3 + 0] = eluf(s0 + ob[0]);
    out[row * 3 + 1] = eluf(s1 + ob[1]);
    out[row * 3 + 2] = eluf(s2 + ob[2]);
  }
}

__global__ void idxcopy_kernel(const int* __restrict__ ei, float* __restrict__ out){
  int i = blockIdx.x * blockDim.x + threadIdx.x;
  if (i < 2 * ECNT) out[i] = (float)ei[i];
}

extern "C" void kernel_launch(void* const* d_in, const int* in_sizes, int n_in,
                              void* d_out, int out_size, void* d_ws, size_t ws_size,
                              hipStream_t stream)
{
  const float* x_in  = (const float*)d_in[0];
  const float* ea_in = (const float*)d_in[1];
  const float* pos_c = (const float*)d_in[2];
  const float* pos_f = (const float*)d_in[3];
  const int*   ei    = (const int*)d_in[4];
  const int*   clus  = (const int*)d_in[5];
  const float* eW0 = (const float*)d_in[7];
  const float* eb0 = (const float*)d_in[8];
  const float* eW1 = (const float*)d_in[9];
  const float* eb1 = (const float*)d_in[10];
  const float* eg  = (const float*)d_in[11];
  const float* ebt = (const float*)d_in[12];
  const float* nW0 = (const float*)d_in[13];
  const float* nb0 = (const float*)d_in[14];
  const float* nW1 = (const float*)d_in[15];
  const float* nb1 = (const float*)d_in[16];
  const float* ng  = (const float*)d_in[17];
  const float* nbt = (const float*)d_in[18];
  const float* dW0 = (const float*)d_in[19];
  const float* db0 = (const float*)d_in[20];
  const float* dW1 = (const float*)d_in[21];
  const float* db1 = (const float*)d_in[22];
  const float* uW0 = (const float*)d_in[23];
  const float* ub0 = (const float*)d_in[24];
  const float* uW1 = (const float*)d_in[25];
  const float* ub1 = (const float*)d_in[26];
  const float* ug  = (const float*)d_in[27];
  const float* ubt = (const float*)d_in[28];
  const float* oW  = (const float*)d_in[29];
  const float* ob  = (const float*)d_in[30];

  char* w = (char*)d_ws;
  auto alloc = [&](size_t bytes) -> char* {
    char* p = w; w += (bytes + 255) & ~(size_t)255; return p;
  };
  u16* ea_s   = (u16*)alloc((size_t)ECNT * HD * 2);
  u16* xa     = (u16*)alloc((size_t)NC * HD * 2);
  u16* xb     = (u16*)alloc((size_t)NF * HD * 2);
  u16* eac    = (u16*)alloc((size_t)NF * HD * 2);
  int* deg    = (int*)alloc((size_t)NF * 4);
  int* rowptr = (int*)alloc((size_t)(NF + 1) * 4);
  int* cursor = (int*)alloc((size_t)NF * 4);
  int* perm   = (int*)alloc((size_t)ECNT * 4);
  int* esrc   = (int*)alloc((size_t)ECNT * 4);
  int* edst   = (int*)alloc((size_t)ECNT * 4);
  int* part   = (int*)alloc((size_t)SCB * 4);
  u16* c_eW0  = (u16*)alloc((size_t)2 * 384 * HD * 2);
  u16* c_eW1  = (u16*)alloc((size_t)2 * HD * HD * 2);
  u16* c_nW0  = (u16*)alloc((size_t)2 * 256 * HD * 2);
  u16* c_nW1  = (u16*)alloc((size_t)2 * HD * HD * 2);
  u16* c_uW0  = (u16*)alloc((size_t)256 * HD * 2);
  u16* c_uW1  = (u16*)alloc((size_t)HD * HD * 2);
  u16* c_dW1  = (u16*)alloc((size_t)HD * HD * 2);

  auto prep = [&](const float* W, u16* o, int K){
    int n = K * HD;
    prep_w_kernel<<<(n + 255) / 256, 256, 0, stream>>>(W, o, K);
  };
  prep(eW0, c_eW0, 384); prep(eW0 + 384 * HD, c_eW0 + 384 * HD, 384);
  prep(eW1, c_eW1, 128); prep(eW1 + HD * HD,  c_eW1 + HD * HD,  128);
  prep(nW0, c_nW0, 256); prep(nW0 + 256 * HD, c_nW0 + 256 * HD, 256);
  prep(nW1, c_nW1, 128); prep(nW1 + HD * HD,  c_nW1 + HD * HD,  128);
  prep(uW0, c_uW0, 256); prep(uW1, c_uW1, 128); prep(dW1, c_dW1, 128);

  f32_to_bf16_vec<<<(NC * HD / 8 + 255) / 256, 256, 0, stream>>>(x_in, xa, NC * HD / 8);

  hipMemsetAsync(deg, 0, (size_t)NF * 4, stream);
  deg_kernel<<<(ECNT + 255) / 256, 256, 0, stream>>>(ei, deg);
  scanA_kernel<<<NB_SCAN, SCB, 0, stream>>>(deg, part);
  scanB_kernel<<<1, SCB, 0, stream>>>(part);
  scanC_kernel<<<NB_SCAN, SCB, 0, stream>>>(deg, part, rowptr);
  hipMemcpyAsync(cursor, rowptr, (size_t)NF * 4, hipMemcpyDeviceToDevice, stream);
  build_perm_kernel<<<(ECNT + 255) / 256, 256, 0, stream>>>(ei, cursor, perm, esrc, edst);
  permute_ea_kernel<<<(ECNT * 16 + 255) / 256, 256, 0, stream>>>(ea_in, perm, ea_s);

  auto grd = [](int rows){ int t = (rows + 63) / 64; return t < 512 ? t : 512; };

  // ---- pass 1 (x = xa, n = NC) ----
  for (int i = 0; i < 2; ++i){
    mfma_mlp<M_EDGE><<<grd(ECNT), 512, 0, stream>>>(
      c_eW0 + (size_t)i * 384 * HD, eb0 + i * HD, c_eW1 + (size_t)i * HD * HD, eb1 + i * HD,
      eg + i * HD, ebt + i * HD, xa, ea_s, esrc, edst, nullptr, nullptr,
      ea_s, ECNT, nullptr, nullptr, nullptr, nullptr);
    mfma_mlp<M_NODE><<<grd(NC), 512, 0, stream>>>(
      c_nW0 + (size_t)i * 256 * HD, nb0 + i * HD, c_nW1 + (size_t)i * HD * HD, nb1 + i * HD,
      ng + i * HD, nbt + i * HD, xa, ea_s, nullptr, nullptr, rowptr, nullptr,
      xa, NC, nullptr, nullptr, nullptr, nullptr);
  }

  // ---- decoder (seg_mean over arange(NF) is identity) ----
  mfma_mlp<M_DEC1><<<grd(NF), 512, 0, stream>>>(
    c_dW1, db1, nullptr, nullptr, nullptr, nullptr,
    nullptr, nullptr, nullptr, nullptr, nullptr, clus,
    eac, NF, dW0, db0, pos_c, pos_f);
  mfma_mlp<M_DEC2><<<grd(NF), 512, 0, stream>>>(
    c_uW0, ub0, c_uW1, ub1, ug, ubt, xa, eac, nullptr, nullptr, nullptr, clus,
    xb, NF, nullptr, nullptr, nullptr, nullptr);

  // ---- pass 2 (x = xb, n = NF) ----
  for (int i = 0; i < 2; ++i){
    mfma_mlp<M_EDGE><<<grd(ECNT), 512, 0, stream>>>(
      c_eW0 + (size_t)i * 384 * HD, eb0 + i * HD, c_eW1 + (size_t)i * HD * HD, eb1 + i * HD,
      eg + i * HD, ebt + i * HD, xb, ea_s, esrc, edst, nullptr, nullptr,
      ea_s, ECNT, nullptr, nullptr, nullptr, nullptr);
    mfma_mlp<M_NODE><<<grd(NF), 512, 0, stream>>>(
      c_nW0 + (size_t)i * 256 * HD, nb0 + i * HD, c_nW1 + (size_t)i * HD * HD, nb1 + i * HD,
      ng + i * HD, nbt + i * HD, xb, ea_s, nullptr, nullptr, rowptr, nullptr,
      xb, NF, nullptr, nullptr, nullptr, nullptr);
  }

  float* out = (float*)d_out;
  outhead_kernel<<<(NF + 3) / 4, 256, 0, stream>>>(xb, oW, ob, out);
  idxcopy_kernel<<<(2 * ECNT + 255) / 256, 256, 0, stream>>>(ei, out + (size_t)NF * OUTD);
}

// Round 3
// 1969.437 us; speedup vs baseline: 6.0794x; 1.5037x over previous
//
#include <hip/hip_runtime.h>

// Decoder_48378511622552 — CSR-sorted, bf16, K=128 MFMA fused GNN decoder (gfx950)
// Round 3: node-factored edge MLP (P/Q precompute), 256-thr blocks, low-VGPR.

#define HD   128
#define NC   50000
#define NF   150000
#define ECNT 400000
#define OUTD 3
#define SCB  512
#define NB_SCAN ((NF + SCB - 1) / SCB)   // 293

typedef unsigned short u16;
typedef unsigned int   u32;
typedef short bf16x8 __attribute__((ext_vector_type(8)));
typedef float f32x4  __attribute__((ext_vector_type(4)));

__device__ __forceinline__ float bf2f(u32 u){ return __uint_as_float(u << 16); }
__device__ __forceinline__ u16 f2bf(float f){
  u32 u = __float_as_uint(f);
  return (u16)((u + 0x7fffu + ((u >> 16) & 1u)) >> 16);   // RNE
}
__device__ __forceinline__ u32 pk2(float a, float b){ return (u32)f2bf(a) | ((u32)f2bf(b) << 16); }
__device__ __forceinline__ u32 addpk(u32 a, u32 b){
  return pk2(bf2f(a & 0xffffu) + bf2f(b & 0xffffu), bf2f(a >> 16) + bf2f(b >> 16));
}
__device__ __forceinline__ float eluf(float x){ return x > 0.f ? x : expm1f(x); }
// swizzled LDS byte offset for a [32][256B] tile
__device__ __forceinline__ int SW(int row, int byte){ return row * 256 + (byte ^ ((row & 7) << 4)); }

// ---------------- prep kernels ----------------

// chunked bf16 weights: out[((k>>3)*128 + j)*8 + (k&7)] = bf16(W[k*128 + j])
__global__ void prep_w_kernel(const float* __restrict__ W, u16* __restrict__ out, int K){
  int idx = blockIdx.x * blockDim.x + threadIdx.x;
  if (idx >= K * HD) return;
  int k = idx / HD, j = idx % HD;
  out[(((k >> 3) * HD + j) << 3) + (k & 7)] = f2bf(W[k * HD + j]);
}

__global__ void f32_to_bf16_vec(const float* __restrict__ in, u16* __restrict__ out, int n8){
  int i = blockIdx.x * blockDim.x + threadIdx.x;
  if (i >= n8) return;
  float4 f0 = ((const float4*)in)[i * 2];
  float4 f1 = ((const float4*)in)[i * 2 + 1];
  ((uint4*)out)[i] = make_uint4(pk2(f0.x,f0.y), pk2(f0.z,f0.w), pk2(f1.x,f1.y), pk2(f1.z,f1.w));
}

__global__ void deg_kernel(const int* __restrict__ ei, int* __restrict__ deg){
  int e = blockIdx.x * blockDim.x + threadIdx.x;
  if (e < ECNT) atomicAdd(&deg[ei[ECNT + e]], 1);
}

__global__ void scanA_kernel(const int* __restrict__ deg, int* __restrict__ part){
  __shared__ int s[SCB];
  int t = threadIdx.x, i = blockIdx.x * SCB + t;
  s[t] = (i < NF) ? deg[i] : 0;
  __syncthreads();
  for (int off = SCB/2; off; off >>= 1){ if (t < off) s[t] += s[t + off]; __syncthreads(); }
  if (t == 0) part[blockIdx.x] = s[0];
}

__global__ void scanB_kernel(int* __restrict__ part){
  __shared__ int s[SCB];
  int t = threadIdx.x;
  int v = (t < NB_SCAN) ? part[t] : 0;
  s[t] = v; __syncthreads();
  for (int off = 1; off < SCB; off <<= 1){
    int x = (t >= off) ? s[t - off] : 0;
    __syncthreads(); s[t] += x; __syncthreads();
  }
  if (t < NB_SCAN) part[t] = s[t] - v;   // exclusive
}

__global__ void scanC_kernel(const int* __restrict__ deg, const int* __restrict__ part,
                             int* __restrict__ rowptr){
  __shared__ int s[SCB];
  int t = threadIdx.x, i = blockIdx.x * SCB + t;
  int v = (i < NF) ? deg[i] : 0;
  s[t] = v; __syncthreads();
  for (int off = 1; off < SCB; off <<= 1){
    int x = (t >= off) ? s[t - off] : 0;
    __syncthreads(); s[t] += x; __syncthreads();
  }
  int excl = part[blockIdx.x] + s[t] - v;
  if (i < NF) rowptr[i] = excl;
  if (i == NF - 1) rowptr[NF] = excl + v;
}

__global__ void build_perm_kernel(const int* __restrict__ ei, int* __restrict__ cursor,
                                  int* __restrict__ perm, int* __restrict__ esrc,
                                  int* __restrict__ edst){
  int e = blockIdx.x * blockDim.x + threadIdx.x;
  if (e >= ECNT) return;
  int sI = ei[e], d = ei[ECNT + e];
  int p = atomicAdd(&cursor[d], 1);
  perm[p] = e; esrc[p] = sI; edst[p] = d;
}

__global__ void permute_ea_kernel(const float* __restrict__ ea_in, const int* __restrict__ perm,
                                  u16* __restrict__ ea_s){
  int i = blockIdx.x * blockDim.x + threadIdx.x;
  if (i >= ECNT * 16) return;
  int p = i >> 4, c = i & 15;
  int e = perm[p];
  const float4* src = (const float4*)(ea_in + (size_t)e * HD + c * 8);
  float4 f0 = src[0], f1 = src[1];
  ((uint4*)ea_s)[(size_t)p * 16 + c] =
      make_uint4(pk2(f0.x,f0.y), pk2(f0.z,f0.w), pk2(f1.x,f1.y), pk2(f1.z,f1.w));
}

// ---------------- unified fused K=128 MFMA MLP ----------------
enum { M_LIN = 0, M_DEC1 = 1, M_EDGE = 2, M_NODE = 3, M_DEC2 = 4 };

// Block: 256 thr = 4 waves; tile 32 rows x 128 cols; wave n-slice 32 cols.
// LIN : out = A @ W0                                   (A = tabA rows, raw store)
// DEC1: A = elu(delta@dW0+db0) inline; out = elu(A@W0 + b0)
// EDGE: A = ea; h = elu(A@W0 + (P[src]+Q[dst]) + b0); o = h@W1 + b1; out = LN(resid + o)
// NODE: A = CSR-mean(ea); addend = T[row];  residual = x[row]
// DEC2: A = eac; addend = XU[clus[row]];    residual = eac[row]
template<int MODE>
__global__ __launch_bounds__(256, 3)
void mlp_kernel(const u16* __restrict__ W0c, const u16* __restrict__ W1c,
                const float* __restrict__ b0, const float* __restrict__ b1,
                const float* __restrict__ gw, const float* __restrict__ bw,
                const u16* __restrict__ tabA, const u16* __restrict__ addP,
                const u16* __restrict__ addQ, const u16* __restrict__ resid,
                const int* __restrict__ esrc, const int* __restrict__ edst,
                const int* __restrict__ rowptr, const u16* __restrict__ eatab,
                const int* __restrict__ clus,
                u16* __restrict__ outp, int n_rows,
                const float* __restrict__ dW0, const float* __restrict__ db0,
                const float* __restrict__ pos_c, const float* __restrict__ pos_f)
{
  constexpr bool HAS2 = (MODE == M_EDGE || MODE == M_NODE || MODE == M_DEC2);

  __shared__ __align__(16) char ldsA [32 * 256];
  __shared__ __align__(16) char ldsPQ[32 * 256];
  __shared__ __align__(16) char ldsH [HAS2 ? 32 * 256 : 16];

  const int tid  = threadIdx.x;
  const int lane = tid & 63;
  const int wid  = tid >> 6;          // 0..3
  const int ln   = lane & 15, kq = lane >> 4;
  const int ncol = wid * 32;

  // layer-1 weight fragments resident (8 frags = 32 VGPR)
  bf16x8 b1f[4][2];
  #pragma unroll
  for (int k0 = 0; k0 < 4; ++k0)
    #pragma unroll
    for (int nt = 0; nt < 2; ++nt)
      b1f[k0][nt] = *(const bf16x8*)(W0c + (((size_t)((k0*4 + kq)*HD + ncol + nt*16 + ln)) << 3));

  float b0v[2] = {0.f, 0.f}, b1v[2] = {0.f, 0.f};
  if constexpr (MODE != M_LIN){
    #pragma unroll
    for (int nt = 0; nt < 2; ++nt) b0v[nt] = b0[ncol + nt*16 + ln];
  }
  float gl0 = 0.f, gl1 = 0.f, bt0 = 0.f, bt1 = 0.f;
  if constexpr (HAS2){
    #pragma unroll
    for (int nt = 0; nt < 2; ++nt) b1v[nt] = b1[ncol + nt*16 + ln];
    gl0 = gw[lane]; gl1 = gw[64 + lane]; bt0 = bw[lane]; bt1 = bw[64 + lane];
  }

  const int tiles = (n_rows + 31) >> 5;

  for (int tile = blockIdx.x; tile < tiles; tile += gridDim.x){
    const int row0 = tile << 5;

    // ---------------- stage ----------------
    if constexpr (MODE == M_EDGE){
      #pragma unroll
      for (int c = 0; c < 2; ++c){
        int i = tid + c * 256;
        int row = i >> 4, kk = i & 15, rg = row0 + row;   // ECNT % 32 == 0
        uint4 va = *(const uint4*)(tabA + (((size_t)rg) << 7) + (kk << 3));
        *(uint4*)(ldsA + SW(row, kk * 16)) = va;
        int sI = esrc[rg], dI = edst[rg];
        uint4 vp = *(const uint4*)(addP + (((size_t)sI) << 7) + (kk << 3));
        uint4 vq = *(const uint4*)(addQ + (((size_t)dI) << 7) + (kk << 3));
        uint4 vs = make_uint4(addpk(vp.x,vq.x), addpk(vp.y,vq.y), addpk(vp.z,vq.z), addpk(vp.w,vq.w));
        *(uint4*)(ldsPQ + SW(row, kk * 16)) = vs;
      }
    } else if constexpr (MODE == M_DEC2){
      #pragma unroll
      for (int c = 0; c < 2; ++c){
        int i = tid + c * 256;
        int row = i >> 4, kk = i & 15, rg = row0 + row;
        if (rg < n_rows){
          *(uint4*)(ldsA + SW(row, kk * 16)) =
              *(const uint4*)(tabA + (((size_t)rg) << 7) + (kk << 3));
          int cl = clus[rg];
          *(uint4*)(ldsPQ + SW(row, kk * 16)) =
              *(const uint4*)(addP + (((size_t)cl) << 7) + (kk << 3));
        }
      }
    } else if constexpr (MODE == M_NODE){
      #pragma unroll
      for (int c = 0; c < 2; ++c){
        int i = tid + c * 256;
        int row = i >> 4, kk = i & 15, rg = row0 + row;
        if (rg < n_rows)
          *(uint4*)(ldsPQ + SW(row, kk * 16)) =
              *(const uint4*)(addP + (((size_t)rg) << 7) + (kk << 3));
      }
      // CSR mean of ea -> ldsA ; wave handles 8 nodes, lane covers cols (2*lane, 2*lane+1)
      for (int s = 0; s < 8; ++s){
        int nd = wid * 8 + s, rg = row0 + nd;
        if (rg < n_rows){
          int rp0 = rowptr[rg], rp1 = rowptr[rg + 1];
          float s0 = 0.f, s1 = 0.f;
          for (int i2 = rp0; i2 < rp1; ++i2){
            u32 u = *(const u32*)(eatab + (((size_t)i2) << 7) + (lane << 1));
            s0 += bf2f(u & 0xffffu); s1 += bf2f(u >> 16);
          }
          int dg = rp1 - rp0;
          float rd = 1.f / (float)(dg > 0 ? dg : 1);
          *(u32*)(ldsA + SW(nd, lane << 2)) = pk2(s0 * rd, s1 * rd);
        }
      }
    } else if constexpr (MODE == M_LIN){
      #pragma unroll
      for (int c = 0; c < 2; ++c){
        int i = tid + c * 256;
        int row = i >> 4, kk = i & 15, rg = row0 + row;
        if (rg < n_rows)
          *(uint4*)(ldsA + SW(row, kk * 16)) =
              *(const uint4*)(tabA + (((size_t)rg) << 7) + (kk << 3));
      }
    } else { // M_DEC1: inline h1 = elu(delta @ dW0 + db0)
      #pragma unroll
      for (int c = 0; c < 2; ++c){
        int i = tid + c * 256;
        int row = i >> 4, c8 = i & 15, rg = row0 + row;
        if (rg < n_rows){
          int cl = clus[rg];
          float d0 = pos_c[cl * 2]     - pos_f[rg * 2];
          float d1 = pos_c[cl * 2 + 1] - pos_f[rg * 2 + 1];
          u32 wq[4];
          #pragma unroll
          for (int q = 0; q < 4; ++q){
            int cc = c8 * 8 + q * 2;
            float va = eluf(fmaf(d0, dW0[cc],     fmaf(d1, dW0[HD + cc],     db0[cc])));
            float vb = eluf(fmaf(d0, dW0[cc + 1], fmaf(d1, dW0[HD + cc + 1], db0[cc + 1])));
            wq[q] = pk2(va, vb);
          }
          *(uint4*)(ldsA + SW(row, c8 * 16)) = make_uint4(wq[0], wq[1], wq[2], wq[3]);
        }
      }
    }
    __syncthreads();   // A: stage visible

    // ---------------- layer 1 (K=128) ----------------
    const f32x4 zz = {0.f, 0.f, 0.f, 0.f};
    f32x4 c1[2][2] = {{zz, zz}, {zz, zz}};
    #pragma unroll
    for (int k0 = 0; k0 < 4; ++k0){
      int r0 = ln, r1 = 16 + ln;
      bf16x8 a0 = *(const bf16x8*)(ldsA + SW(r0, k0 * 64 + (kq << 4)));
      bf16x8 a1 = *(const bf16x8*)(ldsA + SW(r1, k0 * 64 + (kq << 4)));
      c1[0][0] = __builtin_amdgcn_mfma_f32_16x16x32_bf16(a0, b1f[k0][0], c1[0][0], 0, 0, 0);
      c1[0][1] = __builtin_amdgcn_mfma_f32_16x16x32_bf16(a0, b1f[k0][1], c1[0][1], 0, 0, 0);
      c1[1][0] = __builtin_amdgcn_mfma_f32_16x16x32_bf16(a1, b1f[k0][0], c1[1][0], 0, 0, 0);
      c1[1][1] = __builtin_amdgcn_mfma_f32_16x16x32_bf16(a1, b1f[k0][1], c1[1][1], 0, 0, 0);
    }

    if constexpr (HAS2){
      // layer-2 weight frags: reload per tile (anti-hoist via opaque pointer)
      const u16* w1p = W1c;
      asm volatile("" : "+v"(w1p));
      uint4 b2r[4][2];
      #pragma unroll
      for (int k0 = 0; k0 < 4; ++k0)
        #pragma unroll
        for (int nt = 0; nt < 2; ++nt)
          b2r[k0][nt] = *(const uint4*)(w1p + (((size_t)((k0*4 + kq)*HD + ncol + nt*16 + ln)) << 3));

      // h = elu(c1 + addend + b0) -> ldsH
      #pragma unroll
      for (int mi = 0; mi < 2; ++mi)
        #pragma unroll
        for (int nt = 0; nt < 2; ++nt)
          #pragma unroll
          for (int r = 0; r < 4; ++r){
            int row = mi * 16 + kq * 4 + r;
            int col = ncol + nt * 16 + ln;
            float pq = bf2f(*(const u16*)(ldsPQ + SW(row, col * 2)));
            float v  = eluf(c1[mi][nt][r] + pq + b0v[nt]);
            *(u16*)(ldsH + SW(row, col * 2)) = f2bf(v);
          }
      __syncthreads();  // B: h complete, ldsPQ dead

      // ---------------- layer 2 ----------------
      f32x4 c2[2][2] = {{zz, zz}, {zz, zz}};
      #pragma unroll
      for (int k0 = 0; k0 < 4; ++k0){
        int r0 = ln, r1 = 16 + ln;
        bf16x8 a0 = *(const bf16x8*)(ldsH + SW(r0, k0 * 64 + (kq << 4)));
        bf16x8 a1 = *(const bf16x8*)(ldsH + SW(r1, k0 * 64 + (kq << 4)));
        bf16x8 w0f = __builtin_bit_cast(bf16x8, b2r[k0][0]);
        bf16x8 w1f = __builtin_bit_cast(bf16x8, b2r[k0][1]);
        c2[0][0] = __builtin_amdgcn_mfma_f32_16x16x32_bf16(a0, w0f, c2[0][0], 0, 0, 0);
        c2[0][1] = __builtin_amdgcn_mfma_f32_16x16x32_bf16(a0, w1f, c2[0][1], 0, 0, 0);
        c2[1][0] = __builtin_amdgcn_mfma_f32_16x16x32_bf16(a1, w0f, c2[1][0], 0, 0, 0);
        c2[1][1] = __builtin_amdgcn_mfma_f32_16x16x32_bf16(a1, w1f, c2[1][1], 0, 0, 0);
      }
      // r = c2 + b1 -> ldsPQ (dead since sync B)
      #pragma unroll
      for (int mi = 0; mi < 2; ++mi)
        #pragma unroll
        for (int nt = 0; nt < 2; ++nt)
          #pragma unroll
          for (int r = 0; r < 4; ++r){
            int row = mi * 16 + kq * 4 + r;
            int col = ncol + nt * 16 + ln;
            *(u16*)(ldsPQ + SW(row, col * 2)) = f2bf(c2[mi][nt][r] + b1v[nt]);
          }
    } else {
      // LIN / DEC1: r -> ldsPQ
      #pragma unroll
      for (int mi = 0; mi < 2; ++mi)
        #pragma unroll
        for (int nt = 0; nt < 2; ++nt)
          #pragma unroll
          for (int r = 0; r < 4; ++r){
            int row = mi * 16 + kq * 4 + r;
            int col = ncol + nt * 16 + ln;
            float v = c1[mi][nt][r];
            if constexpr (MODE == M_DEC1) v = eluf(v + b0v[nt]);
            *(u16*)(ldsPQ + SW(row, col * 2)) = f2bf(v);
          }
    }
    __syncthreads();  // C: r complete

    // ---------------- LN (+ global residual) + packed coalesced store ----------------
    #pragma unroll
    for (int rr = 0; rr < 8; ++rr){
      int e = wid * 8 + rr, rg = row0 + e;
      float v0 = bf2f(*(const u16*)(ldsPQ + SW(e, lane * 2)));
      float v1 = bf2f(*(const u16*)(ldsPQ + SW(e, (64 + lane) * 2)));
      float y0, y1;
      if constexpr (HAS2){
        if (rg < n_rows){
          v0 += bf2f(resid[(((size_t)rg) << 7) + lane]);
          v1 += bf2f(resid[(((size_t)rg) << 7) + 64 + lane]);
        }
        float s = v0 + v1, q = v0 * v0 + v1 * v1;
        #pragma unroll
        for (int o = 32; o; o >>= 1){ s += __shfl_xor(s, o); q += __shfl_xor(q, o); }
        float mu  = s * (1.f / 128.f);
        float var = q * (1.f / 128.f) - mu * mu;
        float rs  = rsqrtf(var + 1e-5f);
        y0 = (v0 - mu) * rs * gl0 + bt0;
        y1 = (v1 - mu) * rs * gl1 + bt1;
      } else { y0 = v0; y1 = v1; }
      int sl = (lane << 1) & 63;
      float a0s = __shfl(y0, sl), a1s = __shfl(y0, sl + 1);
      float b0s = __shfl(y1, sl), b1s = __shfl(y1, sl + 1);
      float pa = lane < 32 ? a0s : b0s;
      float pb = lane < 32 ? a1s : b1s;
      if (rg < n_rows)
        ((u32*)(outp + (((size_t)rg) << 7)))[lane] = pk2(pa, pb);
    }
    __syncthreads();  // D: LN reads done before next stage overwrites
  }
}

// out0 = elu(x @ oW + ob)
__global__ void outhead_kernel(const u16* __restrict__ x, const float* __restrict__ oW,
                               const float* __restrict__ ob, float* __restrict__ out){
  int row  = (blockIdx.x * blockDim.x + threadIdx.x) >> 6;
  int lane = threadIdx.x & 63;
  if (row >= NF) return;
  float x0 = bf2f(x[((size_t)row << 7) + lane]);
  float x1 = bf2f(x[((size_t)row << 7) + 64 + lane]);
  float s0 = x0 * oW[lane * 3 + 0] + x1 * oW[(64 + lane) * 3 + 0];
  float s1 = x0 * oW[lane * 3 + 1] + x1 * oW[(64 + lane) * 3 + 1];
  float s2 = x0 * oW[lane * 3 + 2] + x1 * oW[(64 + lane) * 3 + 2];
  #pragma unroll
  for (int o = 32; o; o >>= 1){
    s0 += __shfl_xor(s0, o); s1 += __shfl_xor(s1, o); s2 += __shfl_xor(s2, o);
  }
  if (lane == 0){
    out[row * 3 + 0] = eluf(s0 + ob[0]);
    out[row * 3 + 1] = eluf(s1 + ob[1]);
    out[row * 3 + 2] = eluf(s2 + ob[2]);
  }
}

__global__ void idxcopy_kernel(const int* __restrict__ ei, float* __restrict__ out){
  int i = blockIdx.x * blockDim.x + threadIdx.x;
  if (i < 2 * ECNT) out[i] = (float)i < 0 ? 0.f : (float)ei[i];
}

extern "C" void kernel_launch(void* const* d_in, const int* in_sizes, int n_in,
                              void* d_out, int out_size, void* d_ws, size_t ws_size,
                              hipStream_t stream)
{
  const float* x_in  = (const float*)d_in[0];
  const float* ea_in = (const float*)d_in[1];
  const float* pos_c = (const float*)d_in[2];
  const float* pos_f = (const float*)d_in[3];
  const int*   ei    = (const int*)d_in[4];
  const int*   clus  = (const int*)d_in[5];
  const float* eW0 = (const float*)d_in[7];
  const float* eb0 = (const float*)d_in[8];
  const float* eW1 = (const float*)d_in[9];
  const float* eb1 = (const float*)d_in[10];
  const float* eg  = (const float*)d_in[11];
  const float* ebt = (const float*)d_in[12];
  const float* nW0 = (const float*)d_in[13];
  const float* nb0 = (const float*)d_in[14];
  const float* nW1 = (const float*)d_in[15];
  const float* nb1 = (const float*)d_in[16];
  const float* ng  = (const float*)d_in[17];
  const float* nbt = (const float*)d_in[18];
  const float* dW0 = (const float*)d_in[19];
  const float* db0 = (const float*)d_in[20];
  const float* dW1 = (const float*)d_in[21];
  const float* db1 = (const float*)d_in[22];
  const float* uW0 = (const float*)d_in[23];
  const float* ub0 = (const float*)d_in[24];
  const float* uW1 = (const float*)d_in[25];
  const float* ub1 = (const float*)d_in[26];
  const float* ug  = (const float*)d_in[27];
  const float* ubt = (const float*)d_in[28];
  const float* oW  = (const float*)d_in[29];
  const float* ob  = (const float*)d_in[30];

  char* w = (char*)d_ws;
  auto alloc = [&](size_t bytes) -> char* {
    char* p = w; w += (bytes + 255) & ~(size_t)255; return p;
  };
  u16* ea_s   = (u16*)alloc((size_t)ECNT * HD * 2);
  u16* xa     = (u16*)alloc((size_t)NC * HD * 2);
  u16* xb     = (u16*)alloc((size_t)NF * HD * 2);
  u16* eac    = (u16*)alloc((size_t)NF * HD * 2);
  u16* P      = (u16*)alloc((size_t)NF * HD * 2);
  u16* Q      = (u16*)alloc((size_t)NF * HD * 2);
  u16* T      = (u16*)alloc((size_t)NF * HD * 2);
  u16* XU     = (u16*)alloc((size_t)NC * HD * 2);
  int* deg    = (int*)alloc((size_t)NF * 4);
  int* rowptr = (int*)alloc((size_t)(NF + 1) * 4);
  int* cursor = (int*)alloc((size_t)NF * 4);
  int* perm   = (int*)alloc((size_t)ECNT * 4);
  int* esrc   = (int*)alloc((size_t)ECNT * 4);
  int* edst   = (int*)alloc((size_t)ECNT * 4);
  int* part   = (int*)alloc((size_t)SCB * 4);
  u16* c_eW0  = (u16*)alloc((size_t)2 * 384 * HD * 2);
  u16* c_eW1  = (u16*)alloc((size_t)2 * HD * HD * 2);
  u16* c_nW0  = (u16*)alloc((size_t)2 * 256 * HD * 2);
  u16* c_nW1  = (u16*)alloc((size_t)2 * HD * HD * 2);
  u16* c_uW0  = (u16*)alloc((size_t)256 * HD * 2);
  u16* c_uW1  = (u16*)alloc((size_t)HD * HD * 2);
  u16* c_dW1  = (u16*)alloc((size_t)HD * HD * 2);

  auto prep = [&](const float* W, u16* o, int K){
    int n = K * HD;
    prep_w_kernel<<<(n + 255) / 256, 256, 0, stream>>>(W, o, K);
  };
  prep(eW0, c_eW0, 384); prep(eW0 + 384 * HD, c_eW0 + 384 * HD, 384);
  prep(eW1, c_eW1, 128); prep(eW1 + HD * HD,  c_eW1 + HD * HD,  128);
  prep(nW0, c_nW0, 256); prep(nW0 + 256 * HD, c_nW0 + 256 * HD, 256);
  prep(nW1, c_nW1, 128); prep(nW1 + HD * HD,  c_nW1 + HD * HD,  128);
  prep(uW0, c_uW0, 256); prep(uW1, c_uW1, 128); prep(dW1, c_dW1, 128);

  f32_to_bf16_vec<<<(NC * HD / 8 + 255) / 256, 256, 0, stream>>>(x_in, xa, NC * HD / 8);

  hipMemsetAsync(deg, 0, (size_t)NF * 4, stream);
  deg_kernel<<<(ECNT + 255) / 256, 256, 0, stream>>>(ei, deg);
  scanA_kernel<<<NB_SCAN, SCB, 0, stream>>>(deg, part);
  scanB_kernel<<<1, SCB, 0, stream>>>(part);
  scanC_kernel<<<NB_SCAN, SCB, 0, stream>>>(deg, part, rowptr);
  hipMemcpyAsync(cursor, rowptr, (size_t)NF * 4, hipMemcpyDeviceToDevice, stream);
  build_perm_kernel<<<(ECNT + 255) / 256, 256, 0, stream>>>(ei, cursor, perm, esrc, edst);
  permute_ea_kernel<<<(ECNT * 16 + 255) / 256, 256, 0, stream>>>(ea_in, perm, ea_s);

  auto grd = [](int rows){ int t = (rows + 31) / 32; return t < 2048 ? t : 2048; };
  const int KS = 16 * HD * 8;   // u16 offset of one 128-K slice in chunked layout

  // one MP iteration on node table x (n rows): P,Q,LIN-T precompute + EDGE + NODE
  auto mp_iter = [&](u16* x, int n, int i){
    mlp_kernel<M_LIN><<<grd(n), 256, 0, stream>>>(
      c_eW0 + (size_t)i*384*HD,        nullptr, nullptr, nullptr, nullptr, nullptr,
      x, nullptr, nullptr, nullptr, nullptr, nullptr, nullptr, nullptr, nullptr,
      P, n, nullptr, nullptr, nullptr, nullptr);
    mlp_kernel<M_LIN><<<grd(n), 256, 0, stream>>>(
      c_eW0 + (size_t)i*384*HD + KS,   nullptr, nullptr, nullptr, nullptr, nullptr,
      x, nullptr, nullptr, nullptr, nullptr, nullptr, nullptr, nullptr, nullptr,
      Q, n, nullptr, nullptr, nullptr, nullptr);
    mlp_kernel<M_EDGE><<<grd(ECNT), 256, 0, stream>>>(
      c_eW0 + (size_t)i*384*HD + 2*KS, c_eW1 + (size_t)i*HD*HD,
      eb0 + i*HD, eb1 + i*HD, eg + i*HD, ebt + i*HD,
      ea_s, P, Q, ea_s, esrc, edst, nullptr, nullptr, nullptr,
      ea_s, ECNT, nullptr, nullptr, nullptr, nullptr);
    mlp_kernel<M_LIN><<<grd(n), 256, 0, stream>>>(
      c_nW0 + (size_t)i*256*HD,        nullptr, nullptr, nullptr, nullptr, nullptr,
      x, nullptr, nullptr, nullptr, nullptr, nullptr, nullptr, nullptr, nullptr,
      T, n, nullptr, nullptr, nullptr, nullptr);
    mlp_kernel<M_NODE><<<grd(n), 256, 0, stream>>>(
      c_nW0 + (size_t)i*256*HD + KS,   c_nW1 + (size_t)i*HD*HD,
      nb0 + i*HD, nb1 + i*HD, ng + i*HD, nbt + i*HD,
      nullptr, T, nullptr, x, nullptr, nullptr, rowptr, ea_s, nullptr,
      x, n, nullptr, nullptr, nullptr, nullptr);
  };

  // ---- pass 1 on xa ----
  mp_iter(xa, NC, 0);
  mp_iter(xa, NC, 1);

  // ---- decoder ----
  mlp_kernel<M_LIN><<<grd(NC), 256, 0, stream>>>(
    c_uW0 + KS, nullptr, nullptr, nullptr, nullptr, nullptr,
    xa, nullptr, nullptr, nullptr, nullptr, nullptr, nullptr, nullptr, nullptr,
    XU, NC, nullptr, nullptr, nullptr, nullptr);
  mlp_kernel<M_DEC1><<<grd(NF), 256, 0, stream>>>(
    c_dW1, nullptr, db1, nullptr, nullptr, nullptr,
    nullptr, nullptr, nullptr, nullptr, nullptr, nullptr, nullptr, nullptr, clus,
    eac, NF, dW0, db0, pos_c, pos_f);
  mlp_kernel<M_DEC2><<<grd(NF), 256, 0, stream>>>(
    c_uW0, c_uW1, ub0, ub1, ug, ubt,
    eac, XU, nullptr, eac, nullptr, nullptr, nullptr, nullptr, clus,
    xb, NF, nullptr, nullptr, nullptr, nullptr);

  // ---- pass 2 on xb ----
  mp_iter(xb, NF, 0);
  mp_iter(xb, NF, 1);

  float* out = (float*)d_out;
  outhead_kernel<<<(NF + 3) / 4, 256, 0, stream>>>(xb, oW, ob, out);
  idxcopy_kernel<<<(2 * ECNT + 255) / 256, 256, 0, stream>>>(ei, out + (size_t)NF * OUTD);
}